// Round 18
// baseline (2208.324 us; speedup 1.0000x reference)
//
#include <hip/hip_runtime.h>
#include <math.h>

// ---------------------------------------------------------------------------
// Variance-propagating UNet (density prop), NHWC.
// Round 18: revert round-17's 2-pixel-group (VGPR 96 -> occupancy halved,
// regression). Round-16 wave shape restored (16 px x 64 cout, VGPR 64) +
// PING-PONG LDS B staging: 1 barrier per 32-ci chunk instead of 2 (the
// barrier's vmcnt(0) drain was the structural stall; WAR hazard on a buffer
// is separated by the next chunk's barrier). Numerics unchanged (absmax 6144).
// ---------------------------------------------------------------------------

typedef __attribute__((ext_vector_type(8))) short short8;
typedef __attribute__((ext_vector_type(4))) float floatx4;

__device__ __forceinline__ float softplus_f(float x) { return log1pf(expf(x)); }

__device__ __forceinline__ unsigned short f2bf(float x) {
    unsigned int u = __float_as_uint(x);
    u = (u + 0x7FFF + ((u >> 16) & 1)) >> 16;
    return (unsigned short)u;
}
__device__ __forceinline__ float bfval(unsigned short h) {
    return __uint_as_float((unsigned int)h << 16);
}
__device__ __forceinline__ float bf2f_lo(unsigned int u) {
    return __uint_as_float(u << 16);
}
__device__ __forceinline__ float bf2f_hi(unsigned int u) {
    return __uint_as_float(u & 0xFFFF0000u);
}

// ---- weight prep: transposed [tap][co][ci]; w hi, w lo, w^2 (bf16)
__global__ void wprep3_kernel(const float* __restrict__ w,
                              unsigned short* __restrict__ wTh,
                              unsigned short* __restrict__ wTl,
                              unsigned short* __restrict__ wTsq,
                              int Cin, int Cout, int n)
{
    int idx = blockIdx.x * blockDim.x + threadIdx.x;
    if (idx >= n) return;
    int per = Cin * Cout;
    int tap = idx / per;
    int rem = idx - tap * per;
    int co = rem / Cin;
    int ci = rem - co * Cin;
    float v = w[(size_t)(tap * Cin + ci) * Cout + co];
    unsigned short hh = f2bf(v);
    wTh[idx] = hh;
    wTl[idx] = f2bf(v - bfval(hh));
    wTsq[idx] = f2bf(v * v);
}

__global__ void sp_kernel(const float* __restrict__ wsig,
                          float* __restrict__ sp, int n)
{
    int i = blockIdx.x * blockDim.x + threadIdx.x;
    if (i < n) sp[i] = softplus_f(wsig[i]);
}

// ---- t from hi/lo mu + hi/lo s (optional 2nd source at crop offset)
__global__ void t_hl_kernel(const unsigned short* __restrict__ m1h,
                            const unsigned short* __restrict__ m1l,
                            const unsigned short* __restrict__ s1h,
                            const unsigned short* __restrict__ s1l,
                            const unsigned short* __restrict__ m2h,
                            const unsigned short* __restrict__ m2l,
                            const unsigned short* __restrict__ s2h,
                            const unsigned short* __restrict__ s2l,
                            float* __restrict__ t_out,
                            int B_, int Hin, int Win, int Cin1, int Cin2,
                            int H2, int W2, int dh, int dw)
{
    int pix = blockIdx.x * blockDim.x + threadIdx.x;
    int total = B_ * Hin * Win;
    if (pix >= total) return;
    float acc = 0.f;
    {
        const unsigned short* mh = m1h + (size_t)pix * Cin1;
        const unsigned short* ml = m1l + (size_t)pix * Cin1;
        const unsigned short* sh = s1h + (size_t)pix * Cin1;
        const unsigned short* sl = s1l + (size_t)pix * Cin1;
        for (int ci = 0; ci < Cin1; ci += 8) {
            uint4 vmh = *(const uint4*)(mh + ci);
            uint4 vml = *(const uint4*)(ml + ci);
            uint4 vsh = *(const uint4*)(sh + ci);
            uint4 vsl = *(const uint4*)(sl + ci);
            float m0 = bf2f_lo(vmh.x) + bf2f_lo(vml.x), m1 = bf2f_hi(vmh.x) + bf2f_hi(vml.x);
            float m2 = bf2f_lo(vmh.y) + bf2f_lo(vml.y), m3 = bf2f_hi(vmh.y) + bf2f_hi(vml.y);
            float m4 = bf2f_lo(vmh.z) + bf2f_lo(vml.z), m5 = bf2f_hi(vmh.z) + bf2f_hi(vml.z);
            float m6 = bf2f_lo(vmh.w) + bf2f_lo(vml.w), m7 = bf2f_hi(vmh.w) + bf2f_hi(vml.w);
            acc += m0*m0 + m1*m1 + m2*m2 + m3*m3 + m4*m4 + m5*m5 + m6*m6 + m7*m7;
            acc += bf2f_lo(vsh.x) + bf2f_hi(vsh.x) + bf2f_lo(vsh.y) + bf2f_hi(vsh.y)
                 + bf2f_lo(vsh.z) + bf2f_hi(vsh.z) + bf2f_lo(vsh.w) + bf2f_hi(vsh.w);
            acc += bf2f_lo(vsl.x) + bf2f_hi(vsl.x) + bf2f_lo(vsl.y) + bf2f_hi(vsl.y)
                 + bf2f_lo(vsl.z) + bf2f_hi(vsl.z) + bf2f_lo(vsl.w) + bf2f_hi(vsl.w);
        }
    }
    if (Cin2 > 0) {
        int b = pix / (Hin * Win);
        int rem = pix - b * (Hin * Win);
        int h = rem / Win, w = rem - (rem / Win) * Win;
        size_t base = ((size_t)(b * H2 + h + dh) * W2 + (w + dw)) * Cin2;
        const unsigned short* mh = m2h + base;
        const unsigned short* ml = m2l + base;
        const unsigned short* sh = s2h + base;
        const unsigned short* sl = s2l + base;
        for (int ci = 0; ci < Cin2; ci += 8) {
            uint4 vmh = *(const uint4*)(mh + ci);
            uint4 vml = *(const uint4*)(ml + ci);
            uint4 vsh = *(const uint4*)(sh + ci);
            uint4 vsl = *(const uint4*)(sl + ci);
            float m0 = bf2f_lo(vmh.x) + bf2f_lo(vml.x), m1 = bf2f_hi(vmh.x) + bf2f_hi(vml.x);
            float m2 = bf2f_lo(vmh.y) + bf2f_lo(vml.y), m3 = bf2f_hi(vmh.y) + bf2f_hi(vml.y);
            float m4 = bf2f_lo(vmh.z) + bf2f_lo(vml.z), m5 = bf2f_hi(vmh.z) + bf2f_hi(vml.z);
            float m6 = bf2f_lo(vmh.w) + bf2f_lo(vml.w), m7 = bf2f_hi(vmh.w) + bf2f_hi(vml.w);
            acc += m0*m0 + m1*m1 + m2*m2 + m3*m3 + m4*m4 + m5*m5 + m6*m6 + m7*m7;
            acc += bf2f_lo(vsh.x) + bf2f_hi(vsh.x) + bf2f_lo(vsh.y) + bf2f_hi(vsh.y)
                 + bf2f_lo(vsh.z) + bf2f_hi(vsh.z) + bf2f_lo(vsh.w) + bf2f_hi(vsh.w);
            acc += bf2f_lo(vsl.x) + bf2f_hi(vsl.x) + bf2f_lo(vsl.y) + bf2f_hi(vsl.y)
                 + bf2f_lo(vsl.z) + bf2f_hi(vsl.z) + bf2f_lo(vsl.w) + bf2f_hi(vsl.w);
        }
    }
    t_out[pix] = acc;
}

// ---- q9 (dense pad=1): sum t over valid 3x3 taps
__global__ void q9_kernel(const float* __restrict__ t_in,
                          float* __restrict__ q9, int B_, int H, int W)
{
    int pix = blockIdx.x * blockDim.x + threadIdx.x;
    int total = B_ * H * W;
    if (pix >= total) return;
    int b = pix / (H * W);
    int rem = pix - b * (H * W);
    int h = rem / W, w = rem - (rem / W) * W;
    float acc = 0.f;
    for (int kh = 0; kh < 3; kh++) {
        int ih = h + kh - 1;
        if ((unsigned)ih >= (unsigned)H) continue;
        for (int kw = 0; kw < 3; kw++) {
            int iw = w + kw - 1;
            if ((unsigned)iw >= (unsigned)W) continue;
            acc += t_in[(size_t)(b * H + ih) * W + iw];
        }
    }
    q9[pix] = acc;
}

// ---- q9 (unpool): sum t over live (parity) taps; t on input grid [Hin,Win]
__global__ void q9u_kernel(const float* __restrict__ t_in,
                           float* __restrict__ q9,
                           int B_, int Hout, int Wout, int Hin, int Win)
{
    int pix = blockIdx.x * blockDim.x + threadIdx.x;
    int total = B_ * Hout * Wout;
    if (pix >= total) return;
    int b = pix / (Hout * Wout);
    int rem = pix - b * (Hout * Wout);
    int ho = rem / Wout, wo = rem - (rem / Wout) * Wout;
    float acc = 0.f;
    for (int kh = 0; kh < 3; kh++) {
        int uh = ho + kh;
        if (!(uh & 1)) continue;
        int ih = (uh - 1) >> 1;
        for (int kw = 0; kw < 3; kw++) {
            int uw = wo + kw;
            if (!(uw & 1)) continue;
            int iw = (uw - 1) >> 1;
            acc += t_in[(size_t)(b * Hin + ih) * Win + iw];
        }
    }
    q9[pix] = acc;
}

// ---- FUSED MFMA layer: mu (4-MFMA split) + s (2-MFMA hi/lo) + relu gate.
// Each wave: 16 pixels x 64 cout (round-16 shape, VGPR ~64). B tile staged
// into PING-PONG LDS buffers: 1 barrier per chunk (WAR separated by the
// next chunk's barrier). unpoolMode: parity tap validity.
__global__ void __launch_bounds__(256)
fused_layer_kernel(const unsigned short* __restrict__ m1h, const unsigned short* __restrict__ m1l,
                   const unsigned short* __restrict__ s1h, const unsigned short* __restrict__ s1l,
                   const unsigned short* __restrict__ m2h, const unsigned short* __restrict__ m2l,
                   const unsigned short* __restrict__ s2h, const unsigned short* __restrict__ s2l,
                   const float* __restrict__ q9v,
                   const unsigned short* __restrict__ wTh, const unsigned short* __restrict__ wTl,
                   const unsigned short* __restrict__ wTsq,
                   const float* __restrict__ spv_,
                   float* __restrict__ oMf, float* __restrict__ oSf,
                   unsigned short* __restrict__ oMh, unsigned short* __restrict__ oMl,
                   unsigned short* __restrict__ oSh, unsigned short* __restrict__ oSl,
                   int B_, int H, int W, int Hin, int Win, int unpoolMode,
                   int Cin1, int Cin2,
                   int H2, int W2, int dh, int dw, int Cout)
{
    __shared__ unsigned short ldsB[2 * 6912];   // 2 bufs x (3 arrays x 64 co x 36)
    const int tid = threadIdx.x;
    const int lane = tid & 63;
    const int wave = tid >> 6;
    const int total = B_ * H * W;
    const int Cin = Cin1 + Cin2;
    const int ntiles = Cout >> 6;
    const int nPixBlk = (total + 63) >> 6;
    const int nReal = nPixBlk * ntiles;
    const int chunkG = (int)gridDim.x >> 3;
    int gid = ((int)blockIdx.x & 7) * chunkG + ((int)blockIdx.x >> 3);
    if (gid >= nReal) return;                   // block-uniform: barrier-safe
    const int coTile = gid % ntiles;
    const int pixBlk = gid / ntiles;
    const int pixBase = pixBlk * 64 + wave * 16;
    const int coBase = coTile * 64;
    const int row = lane & 15;
    const int quad = lane >> 4;

    const int u0 = tid * 3;

    int P = pixBase + row;
    bool pv = P < total;
    int Pc = pv ? P : 0;
    int pb = Pc / (H * W);
    int r0i = Pc - pb * (H * W);
    int ph = r0i / W;
    int pw = r0i - ph * W;

    floatx4 accM[4], accS[4];
#pragma unroll
    for (int i = 0; i < 4; i++) {
        accM[i] = (floatx4){0.f, 0.f, 0.f, 0.f};
        accS[i] = (floatx4){0.f, 0.f, 0.f, 0.f};
    }
    const short8 zero8 = {0, 0, 0, 0, 0, 0, 0, 0};

    int parity = 0;
    for (int tap = 0; tap < 9; tap++) {
        int kh = tap / 3, kw = tap - kh * 3;
        int ih, iw;
        bool tv;
        if (unpoolMode) {
            int uh = ph + kh, uw = pw + kw;
            tv = pv && (uh & 1) && (uw & 1);
            ih = (uh - 1) >> 1;
            iw = (uw - 1) >> 1;
        } else {
            ih = ph + kh - 1;
            iw = pw + kw - 1;
            tv = pv && ((unsigned)ih < (unsigned)Hin) && ((unsigned)iw < (unsigned)Win);
        }
        if (!tv) { ih = 0; iw = 0; }
        const int nsrc = (Cin2 > 0) ? 2 : 1;
        for (int src = 0; src < nsrc; src++) {
            const int csrc = src ? Cin2 : Cin1;
            const int cofs = src ? Cin1 : 0;
            const unsigned short* aMhp = src ? m2h : m1h;
            const unsigned short* aMlp = src ? m2l : m1l;
            const unsigned short* aShp = src ? s2h : s1h;
            const unsigned short* aSlp = src ? s2l : s1l;
            size_t ab;
            if (src) ab = ((size_t)(pb * H2 + ih + dh) * W2 + (iw + dw)) * (size_t)Cin2 + quad * 8;
            else     ab = ((size_t)(pb * Hin + ih) * Win + iw) * (size_t)Cin1 + quad * 8;
            const size_t wtap = (size_t)(tap * Cout + coBase) * Cin + cofs;
            for (int kb = 0; kb < csrc; kb += 32) {
                unsigned short* buf = &ldsB[parity * 6912];
                // ---- cooperative B staging into ping-pong buffer ----
#pragma unroll
                for (int j = 0; j < 3; j++) {
                    int u = u0 + j;
                    int arr = u >> 8;
                    int rem = u & 255;
                    int co = rem >> 2;
                    int part = rem & 3;
                    const unsigned short* wsrc = (arr == 0) ? wTh : (arr == 1) ? wTl : wTsq;
                    uint4 v = *(const uint4*)(wsrc + wtap + (size_t)co * Cin + kb + part * 8);
                    *(uint4*)(&buf[arr * 2304 + co * 36 + part * 8]) = v;
                }
                __syncthreads();
                // ---- A fragments (per-lane) ----
                short8 aMh = zero8, aMl = zero8, aSh = zero8, aSl = zero8;
                if (tv) {
                    aMh = *(const short8*)(aMhp + ab + kb);
                    aMl = *(const short8*)(aMlp + ab + kb);
                    aSh = *(const short8*)(aShp + ab + kb);
                    aSl = *(const short8*)(aSlp + ab + kb);
                }
#pragma unroll
                for (int nt = 0; nt < 4; nt++) {
                    int lo = (nt * 16 + row) * 36 + quad * 8;
                    short8 bh = *(const short8*)(&buf[lo]);
                    short8 bl = *(const short8*)(&buf[2304 + lo]);
                    short8 bq = *(const short8*)(&buf[4608 + lo]);
                    accM[nt] = __builtin_amdgcn_mfma_f32_16x16x32_bf16(aMh, bh, accM[nt], 0, 0, 0);
                    accM[nt] = __builtin_amdgcn_mfma_f32_16x16x32_bf16(aMl, bh, accM[nt], 0, 0, 0);
                    accM[nt] = __builtin_amdgcn_mfma_f32_16x16x32_bf16(aMh, bl, accM[nt], 0, 0, 0);
                    accM[nt] = __builtin_amdgcn_mfma_f32_16x16x32_bf16(aMl, bl, accM[nt], 0, 0, 0);
                    accS[nt] = __builtin_amdgcn_mfma_f32_16x16x32_bf16(aSh, bq, accS[nt], 0, 0, 0);
                    accS[nt] = __builtin_amdgcn_mfma_f32_16x16x32_bf16(aSl, bq, accS[nt], 0, 0, 0);
                }
                parity ^= 1;
            }
        }
    }

#pragma unroll
    for (int nt = 0; nt < 4; nt++) {
        int co = coBase + nt * 16 + row;
        float spv = spv_[co];
        floatx4 am = accM[nt];
        floatx4 as = accS[nt];
#pragma unroll
        for (int r = 0; r < 4; r++) {
            int P2 = pixBase + quad * 4 + r;
            if (P2 < total) {
                size_t o = (size_t)P2 * Cout + co;
                float mu = am[r];
                float s = q9v[P2] * spv + as[r];
                if (!(mu > 0.f)) { mu = 0.f; s = 0.f; }
                if (oMf) oMf[o] = mu;
                if (oSf) oSf[o] = s;
                if (oMh) {
                    unsigned short mh = f2bf(mu);
                    oMh[o] = mh;
                    oMl[o] = f2bf(mu - bfval(mh));
                    unsigned short sh = f2bf(s);
                    oSh[o] = sh;
                    oSl[o] = f2bf(s - bfval(sh));
                }
            }
        }
    }
}

// ---- first layer (Cin=3): hi/lo outputs
__global__ void conv_input_relu_kernel(const float* __restrict__ x,
                                       const float* __restrict__ w_mu,
                                       const float* __restrict__ w_sig,
                                       unsigned short* __restrict__ m_h,
                                       unsigned short* __restrict__ m_l,
                                       unsigned short* __restrict__ s_h,
                                       unsigned short* __restrict__ s_l,
                                       int B_, int H, int W, int Cin, int Cout)
{
    int co = threadIdx.x;
    int pix = blockIdx.x * blockDim.y + threadIdx.y;
    int total = B_ * H * W;
    if (pix >= total) return;
    int b = pix / (H * W);
    int rem = pix % (H * W);
    int h = rem / W, w = rem % W;

    float mu = 0.f, q = 0.f;
    for (int kh = 0; kh < 3; kh++) {
        int ih = h + kh - 1;
        if (ih < 0 || ih >= H) continue;
        for (int kw = 0; kw < 3; kw++) {
            int iw = w + kw - 1;
            if (iw < 0 || iw >= W) continue;
            const float* xp = x + ((size_t)(b * H + ih) * W + iw) * Cin;
            const float* wp = w_mu + (size_t)((kh * 3 + kw) * Cin) * Cout + co;
            for (int ci = 0; ci < Cin; ci++) {
                float xv = xp[ci];
                mu += xv * wp[(size_t)ci * Cout];
                q += xv * xv;
            }
        }
    }
    float s = q * softplus_f(w_sig[co]);
    if (!(mu > 0.f)) { mu = 0.f; s = 0.f; }
    size_t oidx = (size_t)pix * Cout + co;
    unsigned short mh = f2bf(mu);
    m_h[oidx] = mh;
    m_l[oidx] = f2bf(mu - bfval(mh));
    unsigned short sh = f2bf(s);
    s_h[oidx] = sh;
    s_l[oidx] = f2bf(s - bfval(sh));
}

// ---- pool: fp32 mu for argmax; outputs hi/lo mu + gathered hi/lo s
__global__ void pool_kernel(const float* __restrict__ mu_in,
                            const unsigned short* __restrict__ s_h,
                            const unsigned short* __restrict__ s_l,
                            unsigned short* __restrict__ pm_h,
                            unsigned short* __restrict__ pm_l,
                            unsigned short* __restrict__ ps_h,
                            unsigned short* __restrict__ ps_l,
                            int B_, int H, int W, int C)
{
    int Ho = H / 2, Wo = W / 2;
    size_t total = (size_t)B_ * Ho * Wo * C;
    size_t idx = (size_t)blockIdx.x * blockDim.x + threadIdx.x;
    if (idx >= total) return;
    int c = idx % C;
    size_t t = idx / C;
    int w = t % Wo; t /= Wo;
    int h = t % Ho;
    int b = t / Ho;
    size_t i0 = ((size_t)(b * H + 2 * h) * W + 2 * w) * C + c;
    size_t rowStride = (size_t)W * C;
    float m00 = mu_in[i0], m01 = mu_in[i0 + C];
    float m10 = mu_in[i0 + rowStride], m11 = mu_in[i0 + rowStride + C];
    int best = 0; float bm = m00;
    if (m01 > bm) { bm = m01; best = 1; }
    if (m10 > bm) { bm = m10; best = 2; }
    if (m11 > bm) { bm = m11; best = 3; }
    size_t off = (size_t)(best >> 1) * rowStride + (size_t)(best & 1) * C;
    unsigned short mh = f2bf(bm);
    pm_h[idx] = mh;
    pm_l[idx] = f2bf(bm - bfval(mh));
    ps_h[idx] = s_h[i0 + off];
    ps_l[idx] = s_l[i0 + off];
}

// ---- final 1x1 conv_inter + C=2 softmax density prop (fp32 in)
__global__ void final_kernel(const float* __restrict__ mu_in,
                             const float* __restrict__ s_in,
                             const float* __restrict__ w_mu,
                             const float* __restrict__ w_sig,
                             float* __restrict__ out,
                             int B_, int H, int W, int Cin)
{
    int pix = blockIdx.x * blockDim.x + threadIdx.x;
    int total = B_ * H * W;
    if (pix >= total) return;
    const float* mp = mu_in + (size_t)pix * Cin;
    const float* sp = s_in + (size_t)pix * Cin;
    float mu0 = 0.f, mu1 = 0.f, s0a = 0.f, s1a = 0.f, q = 0.f;
    for (int ci = 0; ci < Cin; ci += 4) {
        float4 m = *(const float4*)(mp + ci);
        float4 s = *(const float4*)(sp + ci);
        float4 wa = *(const float4*)(w_mu + ci * 2);
        float4 wb = *(const float4*)(w_mu + ci * 2 + 4);
        mu0 += m.x * wa.x + m.y * wa.z + m.z * wb.x + m.w * wb.z;
        mu1 += m.x * wa.y + m.y * wa.w + m.z * wb.y + m.w * wb.w;
        s0a += s.x * (wa.x * wa.x) + s.y * (wa.z * wa.z) + s.z * (wb.x * wb.x) + s.w * (wb.z * wb.z);
        s1a += s.x * (wa.y * wa.y) + s.y * (wa.w * wa.w) + s.z * (wb.y * wb.y) + s.w * (wb.w * wb.w);
        q += m.x * m.x + s.x + m.y * m.y + s.y + m.z * m.z + s.z + m.w * m.w + s.w;
    }
    float s0 = q * softplus_f(w_sig[0]) + s0a;
    float s1 = q * softplus_f(w_sig[1]) + s1a;
    float mx = fmaxf(mu0, mu1);
    float e0 = expf(mu0 - mx), e1 = expf(mu1 - mx);
    float inv = 1.f / (e0 + e1);
    float p0 = e0 * inv, p1 = e1 * inv;
    float g00 = p0 - p0 * p0, g01 = -p0 * p1;
    float g10 = -p1 * p0,     g11 = p1 - p1 * p1;
    float so0 = g00 * g00 * s0 + g01 * g01 * s1;
    float so1 = g10 * g10 * s0 + g11 * g11 * s1;
    out[(size_t)pix * 2]     = p0;
    out[(size_t)pix * 2 + 1] = p1;
    size_t off = (size_t)total * 2;
    out[off + (size_t)pix * 2]     = so0;
    out[off + (size_t)pix * 2 + 1] = so1;
}

// ---------------------------------------------------------------------------

extern "C" void kernel_launch(void* const* d_in, const int* in_sizes, int n_in,
                              void* d_out, int out_size, void* d_ws, size_t ws_size,
                              hipStream_t stream)
{
    const float* x = (const float*)d_in[0];
    enum { E1A, E1B, E2A, E2B, BA, BB, D2U, D2A, D2B, D1U, D1A, D1B, FIN, NW };
    const float* wmu[NW];
    const float* wsig[NW];
    for (int i = 0; i < NW; i++) {
        wmu[i]  = (const float*)d_in[1 + 2 * i];
        wsig[i] = (const float*)d_in[2 + 2 * i];
    }

    const int B_ = 4;
    float* ws = (float*)d_ws;
    float* M0  = ws;                         // 4194304 fp32 mu scratch
    float* SF  = ws + 4194304;               // 4194304 fp32 s scratch
    float* tq  = ws + 8388608;               // 65536
    float* q9  = ws + 8454144;               // 65536
    float* spb = ws + 8519680;               // 2048
    unsigned short* us = (unsigned short*)(ws + 8521728);
    const size_t NB = 4194304;
    unsigned short* aMh = us;                // A set
    unsigned short* aMl = us + NB;
    unsigned short* aSh = us + 2 * NB;
    unsigned short* aSl = us + 3 * NB;
    unsigned short* bMh = us + 4 * NB;       // B set
    unsigned short* bMl = us + 5 * NB;
    unsigned short* bSh = us + 6 * NB;
    unsigned short* bSl = us + 7 * NB;
    unsigned short* e1Mh = us + 8 * NB;      // E1 skip
    unsigned short* e1Ml = us + 9 * NB;
    unsigned short* e1Sh = us + 10 * NB;
    unsigned short* e1Sl = us + 11 * NB;
    unsigned short* e2Mh = us + 12 * NB;     // E2 skip (2097152 each)
    unsigned short* e2Ml = e2Mh + 2097152;
    unsigned short* e2Sh = e2Ml + 2097152;
    unsigned short* e2Sl = e2Sh + 2097152;
    unsigned short* wTh  = e2Sl + 2097152;   // 2064384 each (11 layers)
    unsigned short* wTl  = wTh + 2064384;
    unsigned short* wTsq = wTl + 2064384;

    // all 11 conv layers on MFMA
    const int mlay[11]  = {E1B, E2A, E2B, BA, BB, D2U, D2A, D2B, D1U, D1A, D1B};
    const int mcin[11]  = {64, 64, 128, 128, 256, 256, 256, 128, 128, 128, 64};
    const int mcout[11] = {64, 128, 128, 256, 256, 128, 128, 128, 64, 64, 64};
    size_t woff[NW]; int spoff[NW];
    {
        size_t wo = 0; int so = 0;
        for (int i = 0; i < 11; i++) {
            int l = mlay[i];
            woff[l] = wo; spoff[l] = so;
            int n = 9 * mcin[i] * mcout[i];
            wprep3_kernel<<<dim3((n + 255) / 256), dim3(256), 0, stream>>>(
                wmu[l], wTh + wo, wTl + wo, wTsq + wo, mcin[i], mcout[i], n);
            sp_kernel<<<dim3(1), dim3(256), 0, stream>>>(wsig[l], spb + so, mcout[i]);
            wo += n; so += mcout[i];
        }
    }

    // dense fused MFMA layer
    auto flayer = [&](const unsigned short* i_mh, const unsigned short* i_ml,
                      const unsigned short* i_sh, const unsigned short* i_sl, int ci1,
                      const unsigned short* k_mh, const unsigned short* k_ml,
                      const unsigned short* k_sh, const unsigned short* k_sl,
                      int ci2, int h2, int w2, int dh, int dw,
                      int H, int W, int widx, int cout,
                      float* oMf, float* oSf,
                      unsigned short* oMh, unsigned short* oMl,
                      unsigned short* oSh, unsigned short* oSl) {
        int total = B_ * H * W;
        t_hl_kernel<<<dim3((total + 255) / 256), dim3(256), 0, stream>>>(
            i_mh, i_ml, i_sh, i_sl, k_mh, k_ml, k_sh, k_sl, tq,
            B_, H, W, ci1, ci2, h2, w2, dh, dw);
        q9_kernel<<<dim3((total + 255) / 256), dim3(256), 0, stream>>>(tq, q9, B_, H, W);
        int nReal = ((total + 63) / 64) * (cout / 64);
        int G = ((nReal + 7) / 8) * 8;
        fused_layer_kernel<<<dim3(G), dim3(256), 0, stream>>>(
            i_mh, i_ml, i_sh, i_sl, k_mh, k_ml, k_sh, k_sl, q9,
            wTh + woff[widx], wTl + woff[widx], wTsq + woff[widx], spb + spoff[widx],
            oMf, oSf, oMh, oMl, oSh, oSl,
            B_, H, W, H, W, 0, ci1, ci2, h2, w2, dh, dw, cout);
    };

    // unpool fused MFMA layer: input [Hin,Win,ci] -> out [2Hin-1, 2Win-1, cout]
    auto ulayer = [&](const unsigned short* i_mh, const unsigned short* i_ml,
                      const unsigned short* i_sh, const unsigned short* i_sl, int ci,
                      int Hin, int Win, int widx, int cout,
                      unsigned short* oMh, unsigned short* oMl,
                      unsigned short* oSh, unsigned short* oSl) {
        int Hout = 2 * Hin - 1, Wout = 2 * Win - 1;
        int nin = B_ * Hin * Win;
        int total = B_ * Hout * Wout;
        t_hl_kernel<<<dim3((nin + 255) / 256), dim3(256), 0, stream>>>(
            i_mh, i_ml, i_sh, i_sl, nullptr, nullptr, nullptr, nullptr, tq,
            B_, Hin, Win, ci, 0, 0, 0, 0, 0);
        q9u_kernel<<<dim3((total + 255) / 256), dim3(256), 0, stream>>>(
            tq, q9, B_, Hout, Wout, Hin, Win);
        int nReal = ((total + 63) / 64) * (cout / 64);
        int G = ((nReal + 7) / 8) * 8;
        fused_layer_kernel<<<dim3(G), dim3(256), 0, stream>>>(
            i_mh, i_ml, i_sh, i_sl, nullptr, nullptr, nullptr, nullptr, q9,
            wTh + woff[widx], wTl + woff[widx], wTsq + woff[widx], spb + spoff[widx],
            nullptr, nullptr, oMh, oMl, oSh, oSl,
            B_, Hout, Wout, Hin, Win, 1, ci, 0, 0, 0, 0, 0, cout);
    };

    // ---- encoder level 1 ----
    {
        int totalPix = B_ * 128 * 128;
        conv_input_relu_kernel<<<dim3((totalPix + 3) / 4), dim3(64, 4), 0, stream>>>(
            x, wmu[E1A], wsig[E1A], aMh, aMl, aSh, aSl, B_, 128, 128, 3, 64);
    }
    // E1B: A -> E1 skip (hi/lo) + fp32 mu (M0) for pool argmax
    flayer(aMh, aMl, aSh, aSl, 64, nullptr, nullptr, nullptr, nullptr, 0, 0, 0, 0, 0,
           128, 128, E1B, 64, M0, nullptr, e1Mh, e1Ml, e1Sh, e1Sl);
    {
        size_t total = (size_t)B_ * 64 * 64 * 64;
        pool_kernel<<<dim3((total + 255) / 256), dim3(256), 0, stream>>>(
            M0, e1Sh, e1Sl, bMh, bMl, bSh, bSl, B_, 128, 128, 64);
    }
    // ---- encoder level 2 ----
    flayer(bMh, bMl, bSh, bSl, 64, nullptr, nullptr, nullptr, nullptr, 0, 0, 0, 0, 0,
           64, 64, E2A, 128, nullptr, nullptr, aMh, aMl, aSh, aSl);
    flayer(aMh, aMl, aSh, aSl, 128, nullptr, nullptr, nullptr, nullptr, 0, 0, 0, 0, 0,
           64, 64, E2B, 128, M0, nullptr, e2Mh, e2Ml, e2Sh, e2Sl);
    {
        size_t total = (size_t)B_ * 32 * 32 * 128;
        pool_kernel<<<dim3((total + 255) / 256), dim3(256), 0, stream>>>(
            M0, e2Sh, e2Sl, bMh, bMl, bSh, bSl, B_, 64, 64, 128);
    }
    // ---- bottleneck ----
    flayer(bMh, bMl, bSh, bSl, 128, nullptr, nullptr, nullptr, nullptr, 0, 0, 0, 0, 0,
           32, 32, BA, 256, nullptr, nullptr, aMh, aMl, aSh, aSl);
    flayer(aMh, aMl, aSh, aSl, 256, nullptr, nullptr, nullptr, nullptr, 0, 0, 0, 0, 0,
           32, 32, BB, 256, nullptr, nullptr, bMh, bMl, bSh, bSl);
    // ---- decoder level 2 (unpool conv on MFMA, 4-term gates) ----
    ulayer(bMh, bMl, bSh, bSl, 256, 32, 32, D2U, 128, aMh, aMl, aSh, aSl);
    flayer(aMh, aMl, aSh, aSl, 128, e2Mh, e2Ml, e2Sh, e2Sl, 128, 64, 64, 0, 0,
           63, 63, D2A, 128, nullptr, nullptr, bMh, bMl, bSh, bSl);
    flayer(bMh, bMl, bSh, bSl, 128, nullptr, nullptr, nullptr, nullptr, 0, 0, 0, 0, 0,
           63, 63, D2B, 128, nullptr, nullptr, aMh, aMl, aSh, aSl);
    // ---- decoder level 1 (unpool conv on MFMA, 4-term gates) ----
    ulayer(aMh, aMl, aSh, aSl, 128, 63, 63, D1U, 64, bMh, bMl, bSh, bSl);
    flayer(bMh, bMl, bSh, bSl, 64, e1Mh, e1Ml, e1Sh, e1Sl, 64, 128, 128, 1, 1,
           125, 125, D1A, 64, nullptr, nullptr, aMh, aMl, aSh, aSl);
    flayer(aMh, aMl, aSh, aSl, 64, nullptr, nullptr, nullptr, nullptr, 0, 0, 0, 0, 0,
           125, 125, D1B, 64, M0, SF, nullptr, nullptr, nullptr, nullptr);
    // ---- final 1x1 + softmax prop ----
    {
        int totalPix = B_ * 125 * 125;
        final_kernel<<<dim3((totalPix + 63) / 64), dim3(64), 0, stream>>>(
            M0, SF, wmu[FIN], wsig[FIN], (float*)d_out, B_, 125, 125, 64);
    }
}

// Round 19
// 1229.952 us; speedup vs baseline: 1.7955x; 1.7955x over previous
//
#include <hip/hip_runtime.h>
#include <math.h>

// ---------------------------------------------------------------------------
// Variance-propagating UNet (density prop), NHWC.
// FINAL (round-16 configuration, best measured: 1233 us, absmax 6144).
// All 11 convs on MFMA: mu = 4-term split-product (aH*wH+aL*wH+aH*wl+aL*wl,
// residual ~2^-24 -> relu gates fp32-comparable), s = 2-MFMA hi/lo.
// Unpool convs fused via parity tap-validity. Weight tiles staged in LDS
// (coalesced, shared by 4 waves, 2 barriers/chunk — r18 proved 1-barrier
// ping-pong thrashes L2). XCD-swizzled 1D grid. Exact fp32 gates preserved
// through the whole chain; fp32 kept only for pool argmax + final softmax.
// ---------------------------------------------------------------------------

typedef __attribute__((ext_vector_type(8))) short short8;
typedef __attribute__((ext_vector_type(4))) float floatx4;

__device__ __forceinline__ float softplus_f(float x) { return log1pf(expf(x)); }

__device__ __forceinline__ unsigned short f2bf(float x) {
    unsigned int u = __float_as_uint(x);
    u = (u + 0x7FFF + ((u >> 16) & 1)) >> 16;
    return (unsigned short)u;
}
__device__ __forceinline__ float bfval(unsigned short h) {
    return __uint_as_float((unsigned int)h << 16);
}
__device__ __forceinline__ float bf2f_lo(unsigned int u) {
    return __uint_as_float(u << 16);
}
__device__ __forceinline__ float bf2f_hi(unsigned int u) {
    return __uint_as_float(u & 0xFFFF0000u);
}

// ---- weight prep: transposed [tap][co][ci]; w hi, w lo, w^2 (bf16)
__global__ void wprep3_kernel(const float* __restrict__ w,
                              unsigned short* __restrict__ wTh,
                              unsigned short* __restrict__ wTl,
                              unsigned short* __restrict__ wTsq,
                              int Cin, int Cout, int n)
{
    int idx = blockIdx.x * blockDim.x + threadIdx.x;
    if (idx >= n) return;
    int per = Cin * Cout;
    int tap = idx / per;
    int rem = idx - tap * per;
    int co = rem / Cin;
    int ci = rem - co * Cin;
    float v = w[(size_t)(tap * Cin + ci) * Cout + co];
    unsigned short hh = f2bf(v);
    wTh[idx] = hh;
    wTl[idx] = f2bf(v - bfval(hh));
    wTsq[idx] = f2bf(v * v);
}

__global__ void sp_kernel(const float* __restrict__ wsig,
                          float* __restrict__ sp, int n)
{
    int i = blockIdx.x * blockDim.x + threadIdx.x;
    if (i < n) sp[i] = softplus_f(wsig[i]);
}

// ---- t from hi/lo mu + hi/lo s (optional 2nd source at crop offset)
__global__ void t_hl_kernel(const unsigned short* __restrict__ m1h,
                            const unsigned short* __restrict__ m1l,
                            const unsigned short* __restrict__ s1h,
                            const unsigned short* __restrict__ s1l,
                            const unsigned short* __restrict__ m2h,
                            const unsigned short* __restrict__ m2l,
                            const unsigned short* __restrict__ s2h,
                            const unsigned short* __restrict__ s2l,
                            float* __restrict__ t_out,
                            int B_, int Hin, int Win, int Cin1, int Cin2,
                            int H2, int W2, int dh, int dw)
{
    int pix = blockIdx.x * blockDim.x + threadIdx.x;
    int total = B_ * Hin * Win;
    if (pix >= total) return;
    float acc = 0.f;
    {
        const unsigned short* mh = m1h + (size_t)pix * Cin1;
        const unsigned short* ml = m1l + (size_t)pix * Cin1;
        const unsigned short* sh = s1h + (size_t)pix * Cin1;
        const unsigned short* sl = s1l + (size_t)pix * Cin1;
        for (int ci = 0; ci < Cin1; ci += 8) {
            uint4 vmh = *(const uint4*)(mh + ci);
            uint4 vml = *(const uint4*)(ml + ci);
            uint4 vsh = *(const uint4*)(sh + ci);
            uint4 vsl = *(const uint4*)(sl + ci);
            float m0 = bf2f_lo(vmh.x) + bf2f_lo(vml.x), m1 = bf2f_hi(vmh.x) + bf2f_hi(vml.x);
            float m2 = bf2f_lo(vmh.y) + bf2f_lo(vml.y), m3 = bf2f_hi(vmh.y) + bf2f_hi(vml.y);
            float m4 = bf2f_lo(vmh.z) + bf2f_lo(vml.z), m5 = bf2f_hi(vmh.z) + bf2f_hi(vml.z);
            float m6 = bf2f_lo(vmh.w) + bf2f_lo(vml.w), m7 = bf2f_hi(vmh.w) + bf2f_hi(vml.w);
            acc += m0*m0 + m1*m1 + m2*m2 + m3*m3 + m4*m4 + m5*m5 + m6*m6 + m7*m7;
            acc += bf2f_lo(vsh.x) + bf2f_hi(vsh.x) + bf2f_lo(vsh.y) + bf2f_hi(vsh.y)
                 + bf2f_lo(vsh.z) + bf2f_hi(vsh.z) + bf2f_lo(vsh.w) + bf2f_hi(vsh.w);
            acc += bf2f_lo(vsl.x) + bf2f_hi(vsl.x) + bf2f_lo(vsl.y) + bf2f_hi(vsl.y)
                 + bf2f_lo(vsl.z) + bf2f_hi(vsl.z) + bf2f_lo(vsl.w) + bf2f_hi(vsl.w);
        }
    }
    if (Cin2 > 0) {
        int b = pix / (Hin * Win);
        int rem = pix - b * (Hin * Win);
        int h = rem / Win, w = rem - (rem / Win) * Win;
        size_t base = ((size_t)(b * H2 + h + dh) * W2 + (w + dw)) * Cin2;
        const unsigned short* mh = m2h + base;
        const unsigned short* ml = m2l + base;
        const unsigned short* sh = s2h + base;
        const unsigned short* sl = s2l + base;
        for (int ci = 0; ci < Cin2; ci += 8) {
            uint4 vmh = *(const uint4*)(mh + ci);
            uint4 vml = *(const uint4*)(ml + ci);
            uint4 vsh = *(const uint4*)(sh + ci);
            uint4 vsl = *(const uint4*)(sl + ci);
            float m0 = bf2f_lo(vmh.x) + bf2f_lo(vml.x), m1 = bf2f_hi(vmh.x) + bf2f_hi(vml.x);
            float m2 = bf2f_lo(vmh.y) + bf2f_lo(vml.y), m3 = bf2f_hi(vmh.y) + bf2f_hi(vml.y);
            float m4 = bf2f_lo(vmh.z) + bf2f_lo(vml.z), m5 = bf2f_hi(vmh.z) + bf2f_hi(vml.z);
            float m6 = bf2f_lo(vmh.w) + bf2f_lo(vml.w), m7 = bf2f_hi(vmh.w) + bf2f_hi(vml.w);
            acc += m0*m0 + m1*m1 + m2*m2 + m3*m3 + m4*m4 + m5*m5 + m6*m6 + m7*m7;
            acc += bf2f_lo(vsh.x) + bf2f_hi(vsh.x) + bf2f_lo(vsh.y) + bf2f_hi(vsh.y)
                 + bf2f_lo(vsh.z) + bf2f_hi(vsh.z) + bf2f_lo(vsh.w) + bf2f_hi(vsh.w);
            acc += bf2f_lo(vsl.x) + bf2f_hi(vsl.x) + bf2f_lo(vsl.y) + bf2f_hi(vsl.y)
                 + bf2f_lo(vsl.z) + bf2f_hi(vsl.z) + bf2f_lo(vsl.w) + bf2f_hi(vsl.w);
        }
    }
    t_out[pix] = acc;
}

// ---- q9 (dense pad=1): sum t over valid 3x3 taps
__global__ void q9_kernel(const float* __restrict__ t_in,
                          float* __restrict__ q9, int B_, int H, int W)
{
    int pix = blockIdx.x * blockDim.x + threadIdx.x;
    int total = B_ * H * W;
    if (pix >= total) return;
    int b = pix / (H * W);
    int rem = pix - b * (H * W);
    int h = rem / W, w = rem - (rem / W) * W;
    float acc = 0.f;
    for (int kh = 0; kh < 3; kh++) {
        int ih = h + kh - 1;
        if ((unsigned)ih >= (unsigned)H) continue;
        for (int kw = 0; kw < 3; kw++) {
            int iw = w + kw - 1;
            if ((unsigned)iw >= (unsigned)W) continue;
            acc += t_in[(size_t)(b * H + ih) * W + iw];
        }
    }
    q9[pix] = acc;
}

// ---- q9 (unpool): sum t over live (parity) taps; t on input grid [Hin,Win]
__global__ void q9u_kernel(const float* __restrict__ t_in,
                           float* __restrict__ q9,
                           int B_, int Hout, int Wout, int Hin, int Win)
{
    int pix = blockIdx.x * blockDim.x + threadIdx.x;
    int total = B_ * Hout * Wout;
    if (pix >= total) return;
    int b = pix / (Hout * Wout);
    int rem = pix - b * (Hout * Wout);
    int ho = rem / Wout, wo = rem - (rem / Wout) * Wout;
    float acc = 0.f;
    for (int kh = 0; kh < 3; kh++) {
        int uh = ho + kh;
        if (!(uh & 1)) continue;
        int ih = (uh - 1) >> 1;
        for (int kw = 0; kw < 3; kw++) {
            int uw = wo + kw;
            if (!(uw & 1)) continue;
            int iw = (uw - 1) >> 1;
            acc += t_in[(size_t)(b * Hin + ih) * Win + iw];
        }
    }
    q9[pix] = acc;
}

// ---- FUSED MFMA layer: mu (4-MFMA split) + s (2-MFMA hi/lo) + relu gate.
// Each wave: 16 px x 64 cout. Weight tile staged in LDS (coalesced, shared
// by 4 waves), stride 36. unpoolMode: tap validity by parity.
__global__ void __launch_bounds__(256)
fused_layer_kernel(const unsigned short* __restrict__ m1h, const unsigned short* __restrict__ m1l,
                   const unsigned short* __restrict__ s1h, const unsigned short* __restrict__ s1l,
                   const unsigned short* __restrict__ m2h, const unsigned short* __restrict__ m2l,
                   const unsigned short* __restrict__ s2h, const unsigned short* __restrict__ s2l,
                   const float* __restrict__ q9v,
                   const unsigned short* __restrict__ wTh, const unsigned short* __restrict__ wTl,
                   const unsigned short* __restrict__ wTsq,
                   const float* __restrict__ spv_,
                   float* __restrict__ oMf, float* __restrict__ oSf,
                   unsigned short* __restrict__ oMh, unsigned short* __restrict__ oMl,
                   unsigned short* __restrict__ oSh, unsigned short* __restrict__ oSl,
                   int B_, int H, int W, int Hin, int Win, int unpoolMode,
                   int Cin1, int Cin2,
                   int H2, int W2, int dh, int dw, int Cout)
{
    __shared__ unsigned short ldsB[3 * 2304];   // 3 arrays x 64 co x 36 (32+4 pad)
    const int tid = threadIdx.x;
    const int lane = tid & 63;
    const int wave = tid >> 6;
    const int total = B_ * H * W;
    const int Cin = Cin1 + Cin2;
    const int ntiles = Cout >> 6;
    const int nPixBlk = (total + 63) >> 6;
    const int nReal = nPixBlk * ntiles;
    const int chunk = (int)gridDim.x >> 3;
    int gid = ((int)blockIdx.x & 7) * chunk + ((int)blockIdx.x >> 3);
    if (gid >= nReal) return;                   // block-uniform: barrier-safe
    const int coTile = gid % ntiles;
    const int pixBlk = gid / ntiles;
    const int pixBase = pixBlk * 64 + wave * 16;
    const int coBase = coTile * 64;
    const int row = lane & 15;
    const int quad = lane >> 4;

    const int u0 = tid * 3;

    int P = pixBase + row;
    bool pv = P < total;
    int Pc = pv ? P : 0;
    int pb = Pc / (H * W);
    int r0i = Pc - pb * (H * W);
    int ph = r0i / W;
    int pw = r0i - ph * W;

    floatx4 accM[4], accS[4];
#pragma unroll
    for (int i = 0; i < 4; i++) {
        accM[i] = (floatx4){0.f, 0.f, 0.f, 0.f};
        accS[i] = (floatx4){0.f, 0.f, 0.f, 0.f};
    }
    const short8 zero8 = {0, 0, 0, 0, 0, 0, 0, 0};

    for (int tap = 0; tap < 9; tap++) {
        int kh = tap / 3, kw = tap - kh * 3;
        int ih, iw;
        bool tv;
        if (unpoolMode) {
            int uh = ph + kh, uw = pw + kw;
            tv = pv && (uh & 1) && (uw & 1);
            ih = (uh - 1) >> 1;
            iw = (uw - 1) >> 1;
        } else {
            ih = ph + kh - 1;
            iw = pw + kw - 1;
            tv = pv && ((unsigned)ih < (unsigned)Hin) && ((unsigned)iw < (unsigned)Win);
        }
        if (!tv) { ih = 0; iw = 0; }
        const int nsrc = (Cin2 > 0) ? 2 : 1;
        for (int src = 0; src < nsrc; src++) {
            const int csrc = src ? Cin2 : Cin1;
            const int cofs = src ? Cin1 : 0;
            const unsigned short* aMhp = src ? m2h : m1h;
            const unsigned short* aMlp = src ? m2l : m1l;
            const unsigned short* aShp = src ? s2h : s1h;
            const unsigned short* aSlp = src ? s2l : s1l;
            size_t ab;
            if (src) ab = ((size_t)(pb * H2 + ih + dh) * W2 + (iw + dw)) * (size_t)Cin2 + quad * 8;
            else     ab = ((size_t)(pb * Hin + ih) * Win + iw) * (size_t)Cin1 + quad * 8;
            const size_t wtap = (size_t)(tap * Cout + coBase) * Cin + cofs;
            for (int kb = 0; kb < csrc; kb += 32) {
                __syncthreads();
                // ---- cooperative B staging (coalesced) ----
#pragma unroll
                for (int j = 0; j < 3; j++) {
                    int u = u0 + j;
                    int arr = u >> 8;
                    int rem = u & 255;
                    int co = rem >> 2;
                    int part = rem & 3;
                    const unsigned short* wsrc = (arr == 0) ? wTh : (arr == 1) ? wTl : wTsq;
                    uint4 v = *(const uint4*)(wsrc + wtap + (size_t)co * Cin + kb + part * 8);
                    *(uint4*)(&ldsB[arr * 2304 + co * 36 + part * 8]) = v;
                }
                __syncthreads();
                // ---- A fragments (per-lane) ----
                short8 aMh = zero8, aMl = zero8, aSh = zero8, aSl = zero8;
                if (tv) {
                    aMh = *(const short8*)(aMhp + ab + kb);
                    aMl = *(const short8*)(aMlp + ab + kb);
                    aSh = *(const short8*)(aShp + ab + kb);
                    aSl = *(const short8*)(aSlp + ab + kb);
                }
#pragma unroll
                for (int nt = 0; nt < 4; nt++) {
                    int lo = (nt * 16 + row) * 36 + quad * 8;
                    short8 bh = *(const short8*)(&ldsB[lo]);
                    short8 bl = *(const short8*)(&ldsB[2304 + lo]);
                    short8 bq = *(const short8*)(&ldsB[4608 + lo]);
                    accM[nt] = __builtin_amdgcn_mfma_f32_16x16x32_bf16(aMh, bh, accM[nt], 0, 0, 0);
                    accM[nt] = __builtin_amdgcn_mfma_f32_16x16x32_bf16(aMl, bh, accM[nt], 0, 0, 0);
                    accM[nt] = __builtin_amdgcn_mfma_f32_16x16x32_bf16(aMh, bl, accM[nt], 0, 0, 0);
                    accM[nt] = __builtin_amdgcn_mfma_f32_16x16x32_bf16(aMl, bl, accM[nt], 0, 0, 0);
                    accS[nt] = __builtin_amdgcn_mfma_f32_16x16x32_bf16(aSh, bq, accS[nt], 0, 0, 0);
                    accS[nt] = __builtin_amdgcn_mfma_f32_16x16x32_bf16(aSl, bq, accS[nt], 0, 0, 0);
                }
            }
        }
    }

#pragma unroll
    for (int nt = 0; nt < 4; nt++) {
        int co = coBase + nt * 16 + row;
        float spv = spv_[co];
        floatx4 am = accM[nt];
        floatx4 as = accS[nt];
#pragma unroll
        for (int r = 0; r < 4; r++) {
            int P2 = pixBase + quad * 4 + r;
            if (P2 < total) {
                size_t o = (size_t)P2 * Cout + co;
                float mu = am[r];
                float s = q9v[P2] * spv + as[r];
                if (!(mu > 0.f)) { mu = 0.f; s = 0.f; }
                if (oMf) oMf[o] = mu;
                if (oSf) oSf[o] = s;
                if (oMh) {
                    unsigned short mh = f2bf(mu);
                    oMh[o] = mh;
                    oMl[o] = f2bf(mu - bfval(mh));
                    unsigned short sh = f2bf(s);
                    oSh[o] = sh;
                    oSl[o] = f2bf(s - bfval(sh));
                }
            }
        }
    }
}

// ---- first layer (Cin=3): hi/lo outputs
__global__ void conv_input_relu_kernel(const float* __restrict__ x,
                                       const float* __restrict__ w_mu,
                                       const float* __restrict__ w_sig,
                                       unsigned short* __restrict__ m_h,
                                       unsigned short* __restrict__ m_l,
                                       unsigned short* __restrict__ s_h,
                                       unsigned short* __restrict__ s_l,
                                       int B_, int H, int W, int Cin, int Cout)
{
    int co = threadIdx.x;
    int pix = blockIdx.x * blockDim.y + threadIdx.y;
    int total = B_ * H * W;
    if (pix >= total) return;
    int b = pix / (H * W);
    int rem = pix % (H * W);
    int h = rem / W, w = rem % W;

    float mu = 0.f, q = 0.f;
    for (int kh = 0; kh < 3; kh++) {
        int ih = h + kh - 1;
        if (ih < 0 || ih >= H) continue;
        for (int kw = 0; kw < 3; kw++) {
            int iw = w + kw - 1;
            if (iw < 0 || iw >= W) continue;
            const float* xp = x + ((size_t)(b * H + ih) * W + iw) * Cin;
            const float* wp = w_mu + (size_t)((kh * 3 + kw) * Cin) * Cout + co;
            for (int ci = 0; ci < Cin; ci++) {
                float xv = xp[ci];
                mu += xv * wp[(size_t)ci * Cout];
                q += xv * xv;
            }
        }
    }
    float s = q * softplus_f(w_sig[co]);
    if (!(mu > 0.f)) { mu = 0.f; s = 0.f; }
    size_t oidx = (size_t)pix * Cout + co;
    unsigned short mh = f2bf(mu);
    m_h[oidx] = mh;
    m_l[oidx] = f2bf(mu - bfval(mh));
    unsigned short sh = f2bf(s);
    s_h[oidx] = sh;
    s_l[oidx] = f2bf(s - bfval(sh));
}

// ---- pool: fp32 mu for argmax; outputs hi/lo mu + gathered hi/lo s
__global__ void pool_kernel(const float* __restrict__ mu_in,
                            const unsigned short* __restrict__ s_h,
                            const unsigned short* __restrict__ s_l,
                            unsigned short* __restrict__ pm_h,
                            unsigned short* __restrict__ pm_l,
                            unsigned short* __restrict__ ps_h,
                            unsigned short* __restrict__ ps_l,
                            int B_, int H, int W, int C)
{
    int Ho = H / 2, Wo = W / 2;
    size_t total = (size_t)B_ * Ho * Wo * C;
    size_t idx = (size_t)blockIdx.x * blockDim.x + threadIdx.x;
    if (idx >= total) return;
    int c = idx % C;
    size_t t = idx / C;
    int w = t % Wo; t /= Wo;
    int h = t % Ho;
    int b = t / Ho;
    size_t i0 = ((size_t)(b * H + 2 * h) * W + 2 * w) * C + c;
    size_t rowStride = (size_t)W * C;
    float m00 = mu_in[i0], m01 = mu_in[i0 + C];
    float m10 = mu_in[i0 + rowStride], m11 = mu_in[i0 + rowStride + C];
    int best = 0; float bm = m00;
    if (m01 > bm) { bm = m01; best = 1; }
    if (m10 > bm) { bm = m10; best = 2; }
    if (m11 > bm) { bm = m11; best = 3; }
    size_t off = (size_t)(best >> 1) * rowStride + (size_t)(best & 1) * C;
    unsigned short mh = f2bf(bm);
    pm_h[idx] = mh;
    pm_l[idx] = f2bf(bm - bfval(mh));
    ps_h[idx] = s_h[i0 + off];
    ps_l[idx] = s_l[i0 + off];
}

// ---- final 1x1 conv_inter + C=2 softmax density prop (fp32 in)
__global__ void final_kernel(const float* __restrict__ mu_in,
                             const float* __restrict__ s_in,
                             const float* __restrict__ w_mu,
                             const float* __restrict__ w_sig,
                             float* __restrict__ out,
                             int B_, int H, int W, int Cin)
{
    int pix = blockIdx.x * blockDim.x + threadIdx.x;
    int total = B_ * H * W;
    if (pix >= total) return;
    const float* mp = mu_in + (size_t)pix * Cin;
    const float* sp = s_in + (size_t)pix * Cin;
    float mu0 = 0.f, mu1 = 0.f, s0a = 0.f, s1a = 0.f, q = 0.f;
    for (int ci = 0; ci < Cin; ci += 4) {
        float4 m = *(const float4*)(mp + ci);
        float4 s = *(const float4*)(sp + ci);
        float4 wa = *(const float4*)(w_mu + ci * 2);
        float4 wb = *(const float4*)(w_mu + ci * 2 + 4);
        mu0 += m.x * wa.x + m.y * wa.z + m.z * wb.x + m.w * wb.z;
        mu1 += m.x * wa.y + m.y * wa.w + m.z * wb.y + m.w * wb.w;
        s0a += s.x * (wa.x * wa.x) + s.y * (wa.z * wa.z) + s.z * (wb.x * wb.x) + s.w * (wb.z * wb.z);
        s1a += s.x * (wa.y * wa.y) + s.y * (wa.w * wa.w) + s.z * (wb.y * wb.y) + s.w * (wb.w * wb.w);
        q += m.x * m.x + s.x + m.y * m.y + s.y + m.z * m.z + s.z + m.w * m.w + s.w;
    }
    float s0 = q * softplus_f(w_sig[0]) + s0a;
    float s1 = q * softplus_f(w_sig[1]) + s1a;
    float mx = fmaxf(mu0, mu1);
    float e0 = expf(mu0 - mx), e1 = expf(mu1 - mx);
    float inv = 1.f / (e0 + e1);
    float p0 = e0 * inv, p1 = e1 * inv;
    float g00 = p0 - p0 * p0, g01 = -p0 * p1;
    float g10 = -p1 * p0,     g11 = p1 - p1 * p1;
    float so0 = g00 * g00 * s0 + g01 * g01 * s1;
    float so1 = g10 * g10 * s0 + g11 * g11 * s1;
    out[(size_t)pix * 2]     = p0;
    out[(size_t)pix * 2 + 1] = p1;
    size_t off = (size_t)total * 2;
    out[off + (size_t)pix * 2]     = so0;
    out[off + (size_t)pix * 2 + 1] = so1;
}

// ---------------------------------------------------------------------------

extern "C" void kernel_launch(void* const* d_in, const int* in_sizes, int n_in,
                              void* d_out, int out_size, void* d_ws, size_t ws_size,
                              hipStream_t stream)
{
    const float* x = (const float*)d_in[0];
    enum { E1A, E1B, E2A, E2B, BA, BB, D2U, D2A, D2B, D1U, D1A, D1B, FIN, NW };
    const float* wmu[NW];
    const float* wsig[NW];
    for (int i = 0; i < NW; i++) {
        wmu[i]  = (const float*)d_in[1 + 2 * i];
        wsig[i] = (const float*)d_in[2 + 2 * i];
    }

    const int B_ = 4;
    float* ws = (float*)d_ws;
    float* M0  = ws;                         // 4194304 fp32 mu scratch
    float* SF  = ws + 4194304;               // 4194304 fp32 s scratch
    float* tq  = ws + 8388608;               // 65536
    float* q9  = ws + 8454144;               // 65536
    float* spb = ws + 8519680;               // 2048
    unsigned short* us = (unsigned short*)(ws + 8521728);
    const size_t NB = 4194304;
    unsigned short* aMh = us;                // A set
    unsigned short* aMl = us + NB;
    unsigned short* aSh = us + 2 * NB;
    unsigned short* aSl = us + 3 * NB;
    unsigned short* bMh = us + 4 * NB;       // B set
    unsigned short* bMl = us + 5 * NB;
    unsigned short* bSh = us + 6 * NB;
    unsigned short* bSl = us + 7 * NB;
    unsigned short* e1Mh = us + 8 * NB;      // E1 skip
    unsigned short* e1Ml = us + 9 * NB;
    unsigned short* e1Sh = us + 10 * NB;
    unsigned short* e1Sl = us + 11 * NB;
    unsigned short* e2Mh = us + 12 * NB;     // E2 skip (2097152 each)
    unsigned short* e2Ml = e2Mh + 2097152;
    unsigned short* e2Sh = e2Ml + 2097152;
    unsigned short* e2Sl = e2Sh + 2097152;
    unsigned short* wTh  = e2Sl + 2097152;   // 2064384 each (11 layers)
    unsigned short* wTl  = wTh + 2064384;
    unsigned short* wTsq = wTl + 2064384;

    // all 11 conv layers on MFMA
    const int mlay[11]  = {E1B, E2A, E2B, BA, BB, D2U, D2A, D2B, D1U, D1A, D1B};
    const int mcin[11]  = {64, 64, 128, 128, 256, 256, 256, 128, 128, 128, 64};
    const int mcout[11] = {64, 128, 128, 256, 256, 128, 128, 128, 64, 64, 64};
    size_t woff[NW]; int spoff[NW];
    {
        size_t wo = 0; int so = 0;
        for (int i = 0; i < 11; i++) {
            int l = mlay[i];
            woff[l] = wo; spoff[l] = so;
            int n = 9 * mcin[i] * mcout[i];
            wprep3_kernel<<<dim3((n + 255) / 256), dim3(256), 0, stream>>>(
                wmu[l], wTh + wo, wTl + wo, wTsq + wo, mcin[i], mcout[i], n);
            sp_kernel<<<dim3(1), dim3(256), 0, stream>>>(wsig[l], spb + so, mcout[i]);
            wo += n; so += mcout[i];
        }
    }

    // dense fused MFMA layer
    auto flayer = [&](const unsigned short* i_mh, const unsigned short* i_ml,
                      const unsigned short* i_sh, const unsigned short* i_sl, int ci1,
                      const unsigned short* k_mh, const unsigned short* k_ml,
                      const unsigned short* k_sh, const unsigned short* k_sl,
                      int ci2, int h2, int w2, int dh, int dw,
                      int H, int W, int widx, int cout,
                      float* oMf, float* oSf,
                      unsigned short* oMh, unsigned short* oMl,
                      unsigned short* oSh, unsigned short* oSl) {
        int total = B_ * H * W;
        t_hl_kernel<<<dim3((total + 255) / 256), dim3(256), 0, stream>>>(
            i_mh, i_ml, i_sh, i_sl, k_mh, k_ml, k_sh, k_sl, tq,
            B_, H, W, ci1, ci2, h2, w2, dh, dw);
        q9_kernel<<<dim3((total + 255) / 256), dim3(256), 0, stream>>>(tq, q9, B_, H, W);
        int nReal = ((total + 63) / 64) * (cout / 64);
        int G = ((nReal + 7) / 8) * 8;
        fused_layer_kernel<<<dim3(G), dim3(256), 0, stream>>>(
            i_mh, i_ml, i_sh, i_sl, k_mh, k_ml, k_sh, k_sl, q9,
            wTh + woff[widx], wTl + woff[widx], wTsq + woff[widx], spb + spoff[widx],
            oMf, oSf, oMh, oMl, oSh, oSl,
            B_, H, W, H, W, 0, ci1, ci2, h2, w2, dh, dw, cout);
    };

    // unpool fused MFMA layer: input [Hin,Win,ci] -> out [2Hin-1, 2Win-1, cout]
    auto ulayer = [&](const unsigned short* i_mh, const unsigned short* i_ml,
                      const unsigned short* i_sh, const unsigned short* i_sl, int ci,
                      int Hin, int Win, int widx, int cout,
                      unsigned short* oMh, unsigned short* oMl,
                      unsigned short* oSh, unsigned short* oSl) {
        int Hout = 2 * Hin - 1, Wout = 2 * Win - 1;
        int nin = B_ * Hin * Win;
        int total = B_ * Hout * Wout;
        t_hl_kernel<<<dim3((nin + 255) / 256), dim3(256), 0, stream>>>(
            i_mh, i_ml, i_sh, i_sl, nullptr, nullptr, nullptr, nullptr, tq,
            B_, Hin, Win, ci, 0, 0, 0, 0, 0);
        q9u_kernel<<<dim3((total + 255) / 256), dim3(256), 0, stream>>>(
            tq, q9, B_, Hout, Wout, Hin, Win);
        int nReal = ((total + 63) / 64) * (cout / 64);
        int G = ((nReal + 7) / 8) * 8;
        fused_layer_kernel<<<dim3(G), dim3(256), 0, stream>>>(
            i_mh, i_ml, i_sh, i_sl, nullptr, nullptr, nullptr, nullptr, q9,
            wTh + woff[widx], wTl + woff[widx], wTsq + woff[widx], spb + spoff[widx],
            nullptr, nullptr, oMh, oMl, oSh, oSl,
            B_, Hout, Wout, Hin, Win, 1, ci, 0, 0, 0, 0, 0, cout);
    };

    // ---- encoder level 1 ----
    {
        int totalPix = B_ * 128 * 128;
        conv_input_relu_kernel<<<dim3((totalPix + 3) / 4), dim3(64, 4), 0, stream>>>(
            x, wmu[E1A], wsig[E1A], aMh, aMl, aSh, aSl, B_, 128, 128, 3, 64);
    }
    // E1B: A -> E1 skip (hi/lo) + fp32 mu (M0) for pool argmax
    flayer(aMh, aMl, aSh, aSl, 64, nullptr, nullptr, nullptr, nullptr, 0, 0, 0, 0, 0,
           128, 128, E1B, 64, M0, nullptr, e1Mh, e1Ml, e1Sh, e1Sl);
    {
        size_t total = (size_t)B_ * 64 * 64 * 64;
        pool_kernel<<<dim3((total + 255) / 256), dim3(256), 0, stream>>>(
            M0, e1Sh, e1Sl, bMh, bMl, bSh, bSl, B_, 128, 128, 64);
    }
    // ---- encoder level 2 ----
    flayer(bMh, bMl, bSh, bSl, 64, nullptr, nullptr, nullptr, nullptr, 0, 0, 0, 0, 0,
           64, 64, E2A, 128, nullptr, nullptr, aMh, aMl, aSh, aSl);
    flayer(aMh, aMl, aSh, aSl, 128, nullptr, nullptr, nullptr, nullptr, 0, 0, 0, 0, 0,
           64, 64, E2B, 128, M0, nullptr, e2Mh, e2Ml, e2Sh, e2Sl);
    {
        size_t total = (size_t)B_ * 32 * 32 * 128;
        pool_kernel<<<dim3((total + 255) / 256), dim3(256), 0, stream>>>(
            M0, e2Sh, e2Sl, bMh, bMl, bSh, bSl, B_, 64, 64, 128);
    }
    // ---- bottleneck ----
    flayer(bMh, bMl, bSh, bSl, 128, nullptr, nullptr, nullptr, nullptr, 0, 0, 0, 0, 0,
           32, 32, BA, 256, nullptr, nullptr, aMh, aMl, aSh, aSl);
    flayer(aMh, aMl, aSh, aSl, 256, nullptr, nullptr, nullptr, nullptr, 0, 0, 0, 0, 0,
           32, 32, BB, 256, nullptr, nullptr, bMh, bMl, bSh, bSl);
    // ---- decoder level 2 (unpool conv on MFMA, 4-term gates) ----
    ulayer(bMh, bMl, bSh, bSl, 256, 32, 32, D2U, 128, aMh, aMl, aSh, aSl);
    flayer(aMh, aMl, aSh, aSl, 128, e2Mh, e2Ml, e2Sh, e2Sl, 128, 64, 64, 0, 0,
           63, 63, D2A, 128, nullptr, nullptr, bMh, bMl, bSh, bSl);
    flayer(bMh, bMl, bSh, bSl, 128, nullptr, nullptr, nullptr, nullptr, 0, 0, 0, 0, 0,
           63, 63, D2B, 128, nullptr, nullptr, aMh, aMl, aSh, aSl);
    // ---- decoder level 1 (unpool conv on MFMA, 4-term gates) ----
    ulayer(aMh, aMl, aSh, aSl, 128, 63, 63, D1U, 64, bMh, bMl, bSh, bSl);
    flayer(bMh, bMl, bSh, bSl, 64, e1Mh, e1Ml, e1Sh, e1Sl, 64, 128, 128, 1, 1,
           125, 125, D1A, 64, nullptr, nullptr, aMh, aMl, aSh, aSl);
    flayer(aMh, aMl, aSh, aSl, 64, nullptr, nullptr, nullptr, nullptr, 0, 0, 0, 0, 0,
           125, 125, D1B, 64, M0, SF, nullptr, nullptr, nullptr, nullptr);
    // ---- final 1x1 + softmax prop ----
    {
        int totalPix = B_ * 125 * 125;
        final_kernel<<<dim3((totalPix + 63) / 64), dim3(64), 0, stream>>>(
            M0, SF, wmu[FIN], wsig[FIN], (float*)d_out, B_, 125, 125, 64);
    }
}